// Round 10
// baseline (25641.577 us; speedup 1.0000x reference)
//
#include <hip/hip_runtime.h>
#include <cstdint>

#define NB 1024
#define NS 128
#define NH 256

typedef unsigned short ushort_t;
typedef unsigned char uchar_t;

__device__ __forceinline__ void tf2x32(uint32_t k0, uint32_t k1, uint32_t x0, uint32_t x1,
                                       uint32_t &o0, uint32_t &o1) {
  const uint32_t ks2 = k0 ^ k1 ^ 0x1BD11BDAu;
#define TF_R(r) { x0 += x1; x1 = (x1 << (r)) | (x1 >> (32 - (r))); x1 ^= x0; }
  x0 += k0; x1 += k1;
  TF_R(13) TF_R(15) TF_R(26) TF_R(6)
  x0 += k1; x1 += ks2 + 1u;
  TF_R(17) TF_R(29) TF_R(16) TF_R(24)
  x0 += ks2; x1 += k0 + 2u;
  TF_R(13) TF_R(15) TF_R(26) TF_R(6)
  x0 += k0; x1 += k1 + 3u;
  TF_R(17) TF_R(29) TF_R(16) TF_R(24)
  x0 += k1; x1 += ks2 + 4u;
  TF_R(13) TF_R(15) TF_R(26) TF_R(6)
  x0 += ks2; x1 += k0 + 5u;
#undef TF_R
  o0 = x0; o1 = x1;
}

__device__ __forceinline__ float fast_tanh(float x) {
  float ax = fabsf(x);
  float e = __expf(2.0f * ax);
  float r = 1.0f - 2.0f / (e + 1.0f);
  return copysignf(r, x);
}

__device__ __forceinline__ float sigm(float x) { return 1.0f / (1.0f + expf(-x)); }

// ---- 3.5-byte key codec: keep fp32 bits [31:4] with RTN. Planes: hi16, lo8, nibble4 ----
__device__ __forceinline__ float4 key_load(const ushort_t* __restrict__ kh,
                                           const uchar_t* __restrict__ k8,
                                           const ushort_t* __restrict__ kn,
                                           size_t row, int h0) {
  ushort4 hv = *(const ushort4*)(kh + row * 256 + h0);
  uchar4 lv = *(const uchar4*)(k8 + row * 256 + h0);
  uint32_t nv = kn[row * 64 + (h0 >> 2)];
  float4 r;
  r.x = __uint_as_float(((uint32_t)hv.x << 16) | ((uint32_t)lv.x << 8) | ((nv & 0xFu) << 4));
  r.y = __uint_as_float(((uint32_t)hv.y << 16) | ((uint32_t)lv.y << 8) | (((nv >> 4) & 0xFu) << 4));
  r.z = __uint_as_float(((uint32_t)hv.z << 16) | ((uint32_t)lv.z << 8) | (((nv >> 8) & 0xFu) << 4));
  r.w = __uint_as_float(((uint32_t)hv.w << 16) | ((uint32_t)lv.w << 8) | (((nv >> 12) & 0xFu) << 4));
  return r;
}

// ---------------- prep: fold emb_W through input weights; threefry split keys ----------------
__global__ __launch_bounds__(256) void prep_kernel(
    const float* __restrict__ emb_W, const float* __restrict__ enc_W_ih,
    const float* __restrict__ dec_W_ih, const float* __restrict__ dec_start,
    float* __restrict__ F_enc, float* __restrict__ F_dec,
    float* __restrict__ d0proj, uint2* __restrict__ skeys) {
  int j = blockIdx.x * 256 + threadIdx.x;  // 0..1023
  const float* er = enc_W_ih + j * 256;
  const float* dr = dec_W_ih + j * 256;
  float fe0 = 0.f, fe1 = 0.f, fd0 = 0.f, fd1 = 0.f, dp = 0.f;
  for (int e = 0; e < 256; ++e) {
    float we0 = emb_W[e], we1 = emb_W[256 + e];
    float ev = er[e], dv = dr[e];
    fe0 = fmaf(we0, ev, fe0); fe1 = fmaf(we1, ev, fe1);
    fd0 = fmaf(we0, dv, fd0); fd1 = fmaf(we1, dv, fd1);
    dp = fmaf(dec_start[e], dv, dp);
  }
  F_enc[j] = fe0; F_enc[1024 + j] = fe1;
  F_dec[j] = fd0; F_dec[1024 + j] = fd1;
  d0proj[j] = dp;
  if (blockIdx.x == 0 && threadIdx.x < NS) {
    uint32_t o0, o1;
    tf2x32(0u, 42u, 0u, (uint32_t)threadIdx.x, o0, o1);
    skeys[threadIdx.x] = make_uint2(o0, o1);
  }
}

// ---------------- transpose all weight matrices (k-major for coalesced matvec) ----------------
__global__ __launch_bounds__(1024) void transpose_all(
    const float* __restrict__ encW, const float* __restrict__ decW,
    const float* __restrict__ gWk, const float* __restrict__ pWk,
    const float* __restrict__ gWq, const float* __restrict__ pWq,
    float* __restrict__ encT, float* __restrict__ decT, float* __restrict__ WkT,
    float* __restrict__ gWT, float* __restrict__ pWT) {
  int k = blockIdx.x;        // 0..255
  int j = threadIdx.x;       // 0..1023
  encT[k * 1024 + j] = encW[j * 256 + k];
  decT[k * 1024 + j] = decW[j * 256 + k];
  if (j < 512) WkT[k * 512 + j] = (j < 256) ? gWk[j * 256 + k] : pWk[(j - 256) * 256 + k];
  if (j < 256) {
    gWT[k * 256 + j] = gWq[j * 256 + k];
    pWT[k * 256 + j] = pWq[j * 256 + k];
  }
}

__global__ void diag_fill(float* out, float v, int n) {
  int i = blockIdx.x * blockDim.x + threadIdx.x;
  if (i < n) out[i] = v;
}

// ---------------- the whole network: 2 batch rows / block, 512 blocks (2 blocks/CU) ----------------
__global__ __launch_bounds__(1024, 8) void net_kernel(
    const float* __restrict__ x,
    const float* __restrict__ encT, const float* __restrict__ decT,
    const float* __restrict__ enc_b_ih, const float* __restrict__ enc_b_hh,
    const float* __restrict__ dec_b_ih, const float* __restrict__ dec_b_hh,
    const float* __restrict__ F_enc, const float* __restrict__ F_dec,
    const float* __restrict__ d0proj,
    const float* __restrict__ WkT, const float* __restrict__ gkb, const float* __restrict__ pkb,
    const float* __restrict__ gWT, const float* __restrict__ pWT,
    const float* __restrict__ gqb, const float* __restrict__ pqb,
    const float* __restrict__ gvw, const float* __restrict__ gvb,
    const float* __restrict__ pvw, const float* __restrict__ pvb,
    ushort_t* __restrict__ gkh, uchar_t* __restrict__ gk8, ushort_t* __restrict__ gkn,
    ushort_t* __restrict__ pkh, uchar_t* __restrict__ pk8, ushort_t* __restrict__ pkn,
    const uint2* __restrict__ skeys, float* __restrict__ out) {
  __shared__ float h4[256][2];        // h[k][r]
  __shared__ float gx[1024][2];       // gate exchange [j][r]
  __shared__ float xs[2][256];        // x preload per row
  __shared__ float qs[2][256];
  __shared__ float vsm[256];          // v weights (shared by both rows)
  __shared__ float qq[256][2];        // glimpse output, k-major pairs for phase-3 float2 reads
  __shared__ float part[2][8][256];   // qproj partials [r][kh][o] / glimpse partials [r][wave][o]
  __shared__ float wl[2][8];
  __shared__ float lgs[2][NS], sv[2][NS];
  __shared__ int msk[2][NS];
  __shared__ int chs[2];

  const int tid = threadIdx.x;
  const int bb = blockIdx.x * 2;

  // preloads + init
  if (tid < 512) xs[tid >> 8][tid & 255] = x[(size_t)(bb + (tid >> 8)) * 256 + (tid & 255)];
  if (tid < 256) ((int*)msk)[tid] = 0;
  if (tid < 512) ((float*)h4)[tid] = 0.0f;
  const float bse = enc_b_ih[tid] + enc_b_hh[tid];
  const float fae = F_enc[tid], fbe = F_enc[1024 + tid];
  const float bsd = dec_b_ih[tid] + dec_b_hh[tid];
  const float fad = F_dec[tid], fbd = F_dec[1024 + tid];
  const float d0p = d0proj[tid];
  float h_own = 0.0f, c_own = 0.0f;
  __syncthreads();

  // ================= encoder =================
  for (int t = 0; t < NS; ++t) {
    // matvec: thread j = tid computes gate j for both rows
    float2 acc = make_float2(0.f, 0.f);
    {
      const float* wt = encT + tid;
      const float2* hv2 = (const float2*)h4;
#pragma unroll 8
      for (int k = 0; k < 256; ++k) {
        float2 hv = hv2[k];
        float w = wt[(size_t)k * 1024];
        acc.x = fmaf(w, hv.x, acc.x);
        acc.y = fmaf(w, hv.y, acc.y);
      }
    }
    {
      float2 v;
      v.x = acc.x + bse + xs[0][2 * t] * fae + xs[0][2 * t + 1] * fbe;
      v.y = acc.y + bse + xs[1][2 * t] * fae + xs[1][2 * t + 1] * fbe;
      *(float2*)gx[tid] = v;
    }
    __syncthreads();
    if (tid < 512) {
      const int e = tid & 255, r = tid >> 8;
      float gi = gx[e][r], gf = gx[e + 256][r];
      float gg = gx[e + 512][r], go = gx[e + 768][r];
      c_own = sigm(gf) * c_own + sigm(gi) * tanhf(gg);
      h_own = sigm(go) * tanhf(c_own);
      h4[e][r] = h_own;
    }
    __syncthreads();
    // keys(t): 512 threads, 1 column each, both rows (weights loaded once per block)
    if (tid < 512) {
      const int j = tid;
      float2 ka = make_float2(0.f, 0.f);   // .x row0, .y row1
      const float* wk = WkT + j;
      const float2* hv2 = (const float2*)h4;
#pragma unroll 8
      for (int k = 0; k < 256; ++k) {
        float w = wk[(size_t)k * 512];
        float2 hv = hv2[k];
        ka.x = fmaf(w, hv.x, ka.x);
        ka.y = fmaf(w, hv.y, ka.y);
      }
      const bool isp = (j >= 256);
      const int n = isp ? (j - 256) : j;
      float bk = (isp ? pkb : gkb)[n];
      uint32_t a0 = __float_as_uint(ka.x + bk) + 8u;
      uint32_t a1 = __float_as_uint(ka.y + bk) + 8u;
      ushort_t* kh = isp ? pkh : gkh;
      uchar_t* k8 = isp ? pk8 : gk8;
      ushort_t* kn = isp ? pkn : gkn;
      size_t row0 = (size_t)bb * NS + t;
      size_t row1 = (size_t)(bb + 1) * NS + t;
      kh[row0 * 256 + n] = (ushort_t)(a0 >> 16);
      kh[row1 * 256 + n] = (ushort_t)(a1 >> 16);
      k8[row0 * 256 + n] = (uchar_t)(a0 >> 8);
      k8[row1 * 256 + n] = (uchar_t)(a1 >> 8);
      uint32_t nib = ((a0 >> 4) & 0xFu) | (((a1 >> 4) & 0xFu) << 16);
      nib |= ((uint32_t)__shfl_down((int)nib, 1)) << 4;
      nib |= ((uint32_t)__shfl_down((int)nib, 2)) << 8;
      if ((tid & 3) == 0) {
        kn[row0 * 64 + (n >> 2)] = (ushort_t)(nib & 0xFFFFu);
        kn[row1 * 64 + (n >> 2)] = (ushort_t)(nib >> 16);
      }
    }
    __syncthreads();
  }

  // ================= decoder =================
  for (int t = 0; t < NS; ++t) {
    // matvec (dec weights)
    float2 acc = make_float2(0.f, 0.f);
    {
      const float* wt = decT + tid;
      const float2* hv2 = (const float2*)h4;
#pragma unroll 8
      for (int k = 0; k < 256; ++k) {
        float2 hv = hv2[k];
        float w = wt[(size_t)k * 1024];
        acc.x = fmaf(w, hv.x, acc.x);
        acc.y = fmaf(w, hv.y, acc.y);
      }
    }
    {
      float2 v;
      if (t == 0) {
        v.x = acc.x + bsd + d0p;
        v.y = acc.y + bsd + d0p;
      } else {
        int c0 = chs[0], c1 = chs[1];
        v.x = acc.x + bsd + xs[0][2 * c0] * fad + xs[0][2 * c0 + 1] * fbd;
        v.y = acc.y + bsd + xs[1][2 * c1] * fad + xs[1][2 * c1 + 1] * fbd;
      }
      *(float2*)gx[tid] = v;
    }
    __syncthreads();
    if (tid < 512) {
      const int e = tid & 255, r = tid >> 8;
      float gi = gx[e][r], gf = gx[e + 256][r];
      float gg = gx[e + 512][r], go = gx[e + 768][r];
      c_own = sigm(gf) * c_own + sigm(gi) * tanhf(gg);
      h_own = sigm(go) * tanhf(c_own);
      h4[e][r] = h_own;
    }
    __syncthreads();

    const int r2 = tid >> 9;          // row for 8-wave-per-row phases
    const int g512 = tid & 511;
    const int w8 = g512 >> 6;         // wave-in-row 0..7
    const int lane = tid & 63;
    const int h0 = lane * 4;

    // phase 1: qproj-g split-k-2, both rows per thread
    if (tid < 512) {
      const int o = tid & 255, kh_ = tid >> 8;
      const float* wc = gWT + o;
      const float2* hv2 = (const float2*)h4;
      float2 a = make_float2(0.f, 0.f);
      const int kb = kh_ * 128;
#pragma unroll 8
      for (int k = kb; k < kb + 128; ++k) {
        float w = wc[(size_t)k * 256];
        float2 hv = hv2[k];
        a.x = fmaf(w, hv.x, a.x);
        a.y = fmaf(w, hv.y, a.y);
      }
      part[0][kh_][o] = a.x;
      part[1][kh_][o] = a.y;
    }
    __syncthreads();
    // combine qs + gumbel precompute + v-load (disjoint thread ranges, one region)
    if (tid < 512) {
      const int o = tid & 255, r = tid >> 8;
      qs[r][o] = gqb[o] + part[r][0][o] + part[r][1][o];
    } else if (tid < 768) {
      const int idx = tid - 512;
      const int r = idx >> 7, s = idx & 127;
      uint32_t i = (uint32_t)((bb + r) * NS + s);
      uint2 sk = skeys[t];
      uint32_t o0, o1;
      tf2x32(sk.x, sk.y, 0u, i, o0, o1);
      uint32_t bits = o0 ^ o1;
      float u = __uint_as_float((bits >> 9) | 0x3f800000u) - 1.0f;
      u = u + 1.17549435e-38f;
      u = fmaxf(u, 1.17549435e-38f);
      sv[r][s] = -logf(-logf(u));
    } else {
      vsm[tid - 768] = gvw[tid - 768];
    }
    __syncthreads();

    // phase 2: glimpse attention (bounded logits -> plain exp), 8 waves per row, 16 slots each
    {
      const float vbias = gvb[0];
      float4 qv = *(const float4*)&qs[r2][h0];
      float v0 = vsm[h0], v1 = vsm[h0 + 1], v2 = vsm[h0 + 2], v3 = vsm[h0 + 3];
      float l = 0.f;
      float4 acc2 = make_float4(0.f, 0.f, 0.f, 0.f);
      for (int si = 0; si < 16; ++si) {
        int s = w8 * 16 + si;
        if (msk[r2][s]) continue;    // wave-uniform skip
        size_t row = (size_t)(bb + r2) * NS + s;
        float4 kv = key_load(gkh, gk8, gkn, row, h0);
        float p = fast_tanh(qv.x + kv.x) * v0 + fast_tanh(qv.y + kv.y) * v1 +
                  fast_tanh(qv.z + kv.z) * v2 + fast_tanh(qv.w + kv.w) * v3;
#pragma unroll
        for (int off = 32; off; off >>= 1) p += __shfl_xor(p, off);
        float lg = 10.0f * tanhf(p + vbias);
        float pe = expf(lg);         // lg in [-10,10]: safe
        acc2.x = fmaf(pe, kv.x, acc2.x);
        acc2.y = fmaf(pe, kv.y, acc2.y);
        acc2.z = fmaf(pe, kv.z, acc2.z);
        acc2.w = fmaf(pe, kv.w, acc2.w);
        l += pe;
      }
      *(float4*)&part[r2][w8][h0] = acc2;
      if (lane == 0) wl[r2][w8] = l;
    }
    __syncthreads();
    // combine glimpse -> qq; switch v to pointer head
    if (tid < 512) {
      const int o = tid & 255, r = tid >> 8;
      float den = wl[r][0] + wl[r][1] + wl[r][2] + wl[r][3] +
                  wl[r][4] + wl[r][5] + wl[r][6] + wl[r][7];
      float num = part[r][0][o] + part[r][1][o] + part[r][2][o] + part[r][3][o] +
                  part[r][4][o] + part[r][5][o] + part[r][6][o] + part[r][7][o];
      qq[o][r] = num / den;
    } else if (tid < 768) {
      vsm[tid - 512] = pvw[tid - 512];
    }
    __syncthreads();

    // phase 3: qproj-p split-k-2 on qq
    if (tid < 512) {
      const int o = tid & 255, kh_ = tid >> 8;
      const float* wc = pWT + o;
      const float2* qv2 = (const float2*)qq;
      float2 a = make_float2(0.f, 0.f);
      const int kb = kh_ * 128;
#pragma unroll 8
      for (int k = kb; k < kb + 128; ++k) {
        float w = wc[(size_t)k * 256];
        float2 hv = qv2[k];
        a.x = fmaf(w, hv.x, a.x);
        a.y = fmaf(w, hv.y, a.y);
      }
      part[0][kh_][o] = a.x;
      part[1][kh_][o] = a.y;
    }
    __syncthreads();
    if (tid < 512) {
      const int o = tid & 255, r = tid >> 8;
      qs[r][o] = pqb[o] + part[r][0][o] + part[r][1][o];
    }
    __syncthreads();

    // phase 4: pointer logits (mask-skip)
    {
      const float vbias = pvb[0];
      float4 qv = *(const float4*)&qs[r2][h0];
      float v0 = vsm[h0], v1 = vsm[h0 + 1], v2 = vsm[h0 + 2], v3 = vsm[h0 + 3];
      for (int si = 0; si < 16; ++si) {
        int s = w8 * 16 + si;
        if (msk[r2][s]) {
          if (lane == 0) lgs[r2][s] = -100000.0f;
          continue;
        }
        size_t row = (size_t)(bb + r2) * NS + s;
        float4 kv = key_load(pkh, pk8, pkn, row, h0);
        float p = fast_tanh(qv.x + kv.x) * v0 + fast_tanh(qv.y + kv.y) * v1 +
                  fast_tanh(qv.z + kv.z) * v2 + fast_tanh(qv.w + kv.w) * v3;
#pragma unroll
        for (int off = 32; off; off >>= 1) p += __shfl_down(p, off);
        if (lane == 0) lgs[r2][s] = 10.0f * tanhf(p + vbias);
      }
    }
    __syncthreads();

    // fused LSE + gumbel argmax + writeout: wave 0 of each row
    if (g512 < 64) {
      const int r = r2;
      float a0 = lgs[r][lane], a1 = lgs[r][lane + 64];
      float es = expf(a0) + expf(a1);            // exp(-1e5) flushes to 0
      float b0 = a0 + sv[r][lane], b1 = a1 + sv[r][lane + 64];
      float bv; int bi;
      if (b1 > b0) { bv = b1; bi = lane + 64; } else { bv = b0; bi = lane; }
#pragma unroll
      for (int off = 32; off; off >>= 1) {
        es += __shfl_xor(es, off);
        float ov = __shfl_down(bv, off);
        int oi = __shfl_down(bi, off);
        if (ov > bv) { bv = ov; bi = oi; }
      }
      if (lane == 0) {
        int cs = bi;
        out[(size_t)(bb + r) * NS + t] = lgs[r][cs] - logf(es);
        out[(size_t)NB * NS + (size_t)(bb + r) * NS + t] = (float)cs;
        msk[r][cs] = 1;
        chs[r] = cs;
      }
    }
    __syncthreads();
  }
}

extern "C" void kernel_launch(void* const* d_in, const int* in_sizes, int n_in,
                              void* d_out, int out_size, void* d_ws, size_t ws_size,
                              hipStream_t stream) {
  const float* x        = (const float*)d_in[0];
  const float* emb_W    = (const float*)d_in[1];
  const float* enc_W_ih = (const float*)d_in[2];
  const float* enc_W_hh = (const float*)d_in[3];
  const float* enc_b_ih = (const float*)d_in[4];
  const float* enc_b_hh = (const float*)d_in[5];
  const float* dec_W_ih = (const float*)d_in[6];
  const float* dec_W_hh = (const float*)d_in[7];
  const float* dec_b_ih = (const float*)d_in[8];
  const float* dec_b_hh = (const float*)d_in[9];
  const float* g_Wq_w = (const float*)d_in[10];
  const float* g_Wq_b = (const float*)d_in[11];
  const float* g_Wk_w = (const float*)d_in[12];
  const float* g_Wk_b = (const float*)d_in[13];
  const float* g_v_w  = (const float*)d_in[14];
  const float* g_v_b  = (const float*)d_in[15];
  const float* p_Wq_w = (const float*)d_in[16];
  const float* p_Wq_b = (const float*)d_in[17];
  const float* p_Wk_w = (const float*)d_in[18];
  const float* p_Wk_b = (const float*)d_in[19];
  const float* p_v_w  = (const float*)d_in[20];
  const float* p_v_b  = (const float*)d_in[21];
  const float* dec_start = (const float*)d_in[22];
  (void)in_sizes; (void)n_in;

  const size_t KELEM = (size_t)NB * NS * NH;   // 33.55M per head
  char* w = (char*)d_ws;
  size_t off = 0;
  auto alloc = [&](size_t bytes) -> void* {
    void* p = w + off;
    off += (bytes + 255) & ~(size_t)255;
    return p;
  };
  // quantized keys: 3.5 B/elem, both heads = 224 MiB total
  ushort_t* gkh = (ushort_t*)alloc(KELEM * 2);
  uchar_t*  gk8 = (uchar_t*)alloc(KELEM);
  ushort_t* gkn = (ushort_t*)alloc(KELEM / 2);
  ushort_t* pkh = (ushort_t*)alloc(KELEM * 2);
  uchar_t*  pk8 = (uchar_t*)alloc(KELEM);
  ushort_t* pkn = (ushort_t*)alloc(KELEM / 2);

  float* encT   = (float*)alloc(1024 * 256 * 4);
  float* decT   = (float*)alloc(1024 * 256 * 4);
  float* WkT    = (float*)alloc(512 * 256 * 4);
  float* gWT    = (float*)alloc(256 * 256 * 4);
  float* pWT    = (float*)alloc(256 * 256 * 4);
  float* F_enc  = (float*)alloc(2048 * 4);
  float* F_dec  = (float*)alloc(2048 * 4);
  float* d0proj = (float*)alloc(1024 * 4);
  uint2* skeys  = (uint2*)alloc(NS * 8);

  if (off > ws_size) {
    diag_fill<<<(out_size + 255) / 256, 256, 0, stream>>>((float*)d_out, (float)ws_size, out_size);
    return;
  }

  prep_kernel<<<4, 256, 0, stream>>>(emb_W, enc_W_ih, dec_W_ih, dec_start,
                                     F_enc, F_dec, d0proj, skeys);
  transpose_all<<<256, 1024, 0, stream>>>(enc_W_hh, dec_W_hh, g_Wk_w, p_Wk_w,
                                          g_Wq_w, p_Wq_w, encT, decT, WkT, gWT, pWT);
  net_kernel<<<NB / 2, 1024, 0, stream>>>(
      x, encT, decT, enc_b_ih, enc_b_hh, dec_b_ih, dec_b_hh,
      F_enc, F_dec, d0proj, WkT, g_Wk_b, p_Wk_b,
      gWT, pWT, g_Wq_b, p_Wq_b, g_v_w, g_v_b, p_v_w, p_v_b,
      gkh, gk8, gkn, pkh, pk8, pkn, skeys, (float*)d_out);
}

// Round 11
// 10830.057 us; speedup vs baseline: 2.3676x; 2.3676x over previous
//
#include <hip/hip_runtime.h>
#include <cstdint>

#define NB 1024
#define NS 128
#define NH 256

typedef unsigned short ushort_t;
typedef unsigned char uchar_t;

__device__ __forceinline__ void tf2x32(uint32_t k0, uint32_t k1, uint32_t x0, uint32_t x1,
                                       uint32_t &o0, uint32_t &o1) {
  const uint32_t ks2 = k0 ^ k1 ^ 0x1BD11BDAu;
#define TF_R(r) { x0 += x1; x1 = (x1 << (r)) | (x1 >> (32 - (r))); x1 ^= x0; }
  x0 += k0; x1 += k1;
  TF_R(13) TF_R(15) TF_R(26) TF_R(6)
  x0 += k1; x1 += ks2 + 1u;
  TF_R(17) TF_R(29) TF_R(16) TF_R(24)
  x0 += ks2; x1 += k0 + 2u;
  TF_R(13) TF_R(15) TF_R(26) TF_R(6)
  x0 += k0; x1 += k1 + 3u;
  TF_R(17) TF_R(29) TF_R(16) TF_R(24)
  x0 += k1; x1 += ks2 + 4u;
  TF_R(13) TF_R(15) TF_R(26) TF_R(6)
  x0 += ks2; x1 += k0 + 5u;
#undef TF_R
  o0 = x0; o1 = x1;
}

__device__ __forceinline__ float fast_tanh(float x) {
  float ax = fabsf(x);
  float e = __expf(2.0f * ax);
  float r = 1.0f - 2.0f / (e + 1.0f);
  return copysignf(r, x);
}

__device__ __forceinline__ float sigm(float x) { return 1.0f / (1.0f + expf(-x)); }

// ---- 3.5-byte key codec: keep fp32 bits [31:4] with RTN. Planes: hi16, lo8, nibble4 ----
__device__ __forceinline__ float4 key_load(const ushort_t* __restrict__ kh,
                                           const uchar_t* __restrict__ k8,
                                           const ushort_t* __restrict__ kn,
                                           size_t row, int h0) {
  ushort4 hv = *(const ushort4*)(kh + row * 256 + h0);
  uchar4 lv = *(const uchar4*)(k8 + row * 256 + h0);
  uint32_t nv = kn[row * 64 + (h0 >> 2)];
  float4 r;
  r.x = __uint_as_float(((uint32_t)hv.x << 16) | ((uint32_t)lv.x << 8) | ((nv & 0xFu) << 4));
  r.y = __uint_as_float(((uint32_t)hv.y << 16) | ((uint32_t)lv.y << 8) | (((nv >> 4) & 0xFu) << 4));
  r.z = __uint_as_float(((uint32_t)hv.z << 16) | ((uint32_t)lv.z << 8) | (((nv >> 8) & 0xFu) << 4));
  r.w = __uint_as_float(((uint32_t)hv.w << 16) | ((uint32_t)lv.w << 8) | (((nv >> 12) & 0xFu) << 4));
  return r;
}

// ---------------- prep: fold emb_W through input weights; threefry split keys ----------------
__global__ __launch_bounds__(256) void prep_kernel(
    const float* __restrict__ emb_W, const float* __restrict__ enc_W_ih,
    const float* __restrict__ dec_W_ih, const float* __restrict__ dec_start,
    float* __restrict__ F_enc, float* __restrict__ F_dec,
    float* __restrict__ d0proj, uint2* __restrict__ skeys) {
  int j = blockIdx.x * 256 + threadIdx.x;  // 0..1023
  const float* er = enc_W_ih + j * 256;
  const float* dr = dec_W_ih + j * 256;
  float fe0 = 0.f, fe1 = 0.f, fd0 = 0.f, fd1 = 0.f, dp = 0.f;
  for (int e = 0; e < 256; ++e) {
    float we0 = emb_W[e], we1 = emb_W[256 + e];
    float ev = er[e], dv = dr[e];
    fe0 = fmaf(we0, ev, fe0); fe1 = fmaf(we1, ev, fe1);
    fd0 = fmaf(we0, dv, fd0); fd1 = fmaf(we1, dv, fd1);
    dp = fmaf(dec_start[e], dv, dp);
  }
  F_enc[j] = fe0; F_enc[1024 + j] = fe1;
  F_dec[j] = fd0; F_dec[1024 + j] = fd1;
  d0proj[j] = dp;
  if (blockIdx.x == 0 && threadIdx.x < NS) {
    uint32_t o0, o1;
    tf2x32(0u, 42u, 0u, (uint32_t)threadIdx.x, o0, o1);
    skeys[threadIdx.x] = make_uint2(o0, o1);
  }
}

// ---------------- transpose all weight matrices (k-major for coalesced matvec) ----------------
__global__ __launch_bounds__(1024) void transpose_all(
    const float* __restrict__ encW, const float* __restrict__ decW,
    const float* __restrict__ gWk, const float* __restrict__ pWk,
    const float* __restrict__ gWq, const float* __restrict__ pWq,
    float* __restrict__ encT, float* __restrict__ decT, float* __restrict__ WkT,
    float* __restrict__ gWT, float* __restrict__ pWT) {
  int k = blockIdx.x;        // 0..255
  int j = threadIdx.x;       // 0..1023
  encT[k * 1024 + j] = encW[j * 256 + k];
  decT[k * 1024 + j] = decW[j * 256 + k];
  if (j < 512) WkT[k * 512 + j] = (j < 256) ? gWk[j * 256 + k] : pWk[(j - 256) * 256 + k];
  if (j < 256) {
    gWT[k * 256 + j] = gWq[j * 256 + k];
    pWT[k * 256 + j] = pWq[j * 256 + k];
  }
}

__global__ void diag_fill(float* out, float v, int n) {
  int i = blockIdx.x * blockDim.x + threadIdx.x;
  if (i < n) out[i] = v;
}

// ---------------- the whole network: one plain kernel, 4 batch rows / block ----------------
__global__ __launch_bounds__(1024) void net_kernel(
    const float* __restrict__ x,
    const float* __restrict__ encT, const float* __restrict__ decT,
    const float* __restrict__ enc_b_ih, const float* __restrict__ enc_b_hh,
    const float* __restrict__ dec_b_ih, const float* __restrict__ dec_b_hh,
    const float* __restrict__ F_enc, const float* __restrict__ F_dec,
    const float* __restrict__ d0proj,
    const float* __restrict__ WkT, const float* __restrict__ gkb, const float* __restrict__ pkb,
    const float* __restrict__ gWT, const float* __restrict__ pWT,
    const float* __restrict__ gqb, const float* __restrict__ pqb,
    const float* __restrict__ gvw, const float* __restrict__ gvb,
    const float* __restrict__ pvw, const float* __restrict__ pvb,
    ushort_t* __restrict__ gkh, uchar_t* __restrict__ gk8, ushort_t* __restrict__ gkn,
    ushort_t* __restrict__ pkh, uchar_t* __restrict__ pk8, ushort_t* __restrict__ pkn,
    const uint2* __restrict__ skeys, float* __restrict__ out) {
  __shared__ float h4[256][4];        // h4[k][r] — float4 broadcast per k
  __shared__ float gx[1024][4];       // gate exchange [j][r]
  __shared__ float xs[1024];          // x preload [r*256 + e]
  __shared__ float qs[4][256], vsm[4][256];
  __shared__ float qq[256][4];        // glimpse output, k-major for 4-row float4 reads
  __shared__ float part[4][4][256];   // 16 KB scratch: qproj/keys partials, glimpse partials
  __shared__ float wl[4][4];
  __shared__ float lgs[4][NS], sv[4][NS];
  __shared__ int msk[4][NS];
  __shared__ int chs[4];

  const int tid = threadIdx.x;
  const int r_own = tid >> 8, e_own = tid & 255;
  const int bb = blockIdx.x * 4;

  // preloads + init
  xs[tid] = x[(size_t)(bb + r_own) * 256 + e_own];
  if (tid < 512) ((int*)msk)[tid] = 0;
  ((float*)h4)[tid] = 0.0f;
  const float bse = enc_b_ih[tid] + enc_b_hh[tid];
  const float fae = F_enc[tid], fbe = F_enc[1024 + tid];
  const float bsd = dec_b_ih[tid] + dec_b_hh[tid];
  const float fad = F_dec[tid], fbd = F_dec[1024 + tid];
  const float d0p = d0proj[tid];
  float h_own = 0.0f, c_own = 0.0f;
  __syncthreads();

  // ================= encoder =================
  for (int t = 0; t < NS; ++t) {
    // LSTM matvec: thread j=tid computes gate j for all 4 rows
    float4 acc = make_float4(0.f, 0.f, 0.f, 0.f);
    {
      const float* wt = encT + tid;
      const float4* hv4 = (const float4*)h4;
#pragma unroll 8
      for (int k = 0; k < 256; ++k) {
        float4 hv = hv4[k];
        float w = wt[(size_t)k * 1024];
        acc.x = fmaf(w, hv.x, acc.x);
        acc.y = fmaf(w, hv.y, acc.y);
        acc.z = fmaf(w, hv.z, acc.z);
        acc.w = fmaf(w, hv.w, acc.w);
      }
    }
    {
      float4 v;
      v.x = acc.x + bse + xs[2 * t] * fae + xs[2 * t + 1] * fbe;
      v.y = acc.y + bse + xs[256 + 2 * t] * fae + xs[256 + 2 * t + 1] * fbe;
      v.z = acc.z + bse + xs[512 + 2 * t] * fae + xs[512 + 2 * t + 1] * fbe;
      v.w = acc.w + bse + xs[768 + 2 * t] * fae + xs[768 + 2 * t + 1] * fbe;
      *(float4*)gx[tid] = v;
    }
    __syncthreads();
    {
      float gi = gx[e_own][r_own], gf = gx[e_own + 256][r_own];
      float gg = gx[e_own + 512][r_own], go = gx[e_own + 768][r_own];
      c_own = sigm(gf) * c_own + sigm(gi) * tanhf(gg);
      h_own = sigm(go) * tanhf(c_own);
      h4[e_own][r_own] = h_own;
    }
    __syncthreads();
    // keys(t) partials: split-k-2, one weight load feeds all 4 rows
    {
      const int j = tid & 511;
      const int kh2 = tid >> 9;
      const float* wk = WkT + (size_t)kh2 * 128 * 512 + j;
      const float4* hv4 = (const float4*)h4;
      float4 ka = make_float4(0.f, 0.f, 0.f, 0.f);
#pragma unroll 8
      for (int k = 0; k < 128; ++k) {
        float w = wk[(size_t)k * 512];
        float4 hv = hv4[kh2 * 128 + k];
        ka.x = fmaf(w, hv.x, ka.x);
        ka.y = fmaf(w, hv.y, ka.y);
        ka.z = fmaf(w, hv.z, ka.z);
        ka.w = fmaf(w, hv.w, ka.w);
      }
      ((float4*)part)[(size_t)kh2 * 512 + j] = ka;
    }
    __syncthreads();
    // keys combine + quantized store (packing verified: quad-aligned, no cross-wave shfl)
    if (tid < 512) {
      const int j = tid;
      const float4* pf = (const float4*)part;
      float4 k0 = pf[j], k1 = pf[512 + j];
      const bool isp = (j >= 256);
      const int n = isp ? (j - 256) : j;
      float bk = (isp ? pkb : gkb)[n];
      uint32_t a0 = __float_as_uint(k0.x + k1.x + bk) + 8u;
      uint32_t a1 = __float_as_uint(k0.y + k1.y + bk) + 8u;
      uint32_t a2 = __float_as_uint(k0.z + k1.z + bk) + 8u;
      uint32_t a3 = __float_as_uint(k0.w + k1.w + bk) + 8u;
      ushort_t* kh = isp ? pkh : gkh;
      uchar_t* k8 = isp ? pk8 : gk8;
      ushort_t* kn = isp ? pkn : gkn;
      size_t r0 = (size_t)bb * NS + t, r1 = r0 + NS, r2 = r1 + NS, r3 = r2 + NS;
      kh[r0 * 256 + n] = (ushort_t)(a0 >> 16);
      kh[r1 * 256 + n] = (ushort_t)(a1 >> 16);
      kh[r2 * 256 + n] = (ushort_t)(a2 >> 16);
      kh[r3 * 256 + n] = (ushort_t)(a3 >> 16);
      k8[r0 * 256 + n] = (uchar_t)(a0 >> 8);
      k8[r1 * 256 + n] = (uchar_t)(a1 >> 8);
      k8[r2 * 256 + n] = (uchar_t)(a2 >> 8);
      k8[r3 * 256 + n] = (uchar_t)(a3 >> 8);
      uint32_t nibA = ((a0 >> 4) & 0xFu) | (((a1 >> 4) & 0xFu) << 16);
      uint32_t nibB = ((a2 >> 4) & 0xFu) | (((a3 >> 4) & 0xFu) << 16);
      nibA |= ((uint32_t)__shfl_down((int)nibA, 1)) << 4;
      nibA |= ((uint32_t)__shfl_down((int)nibA, 2)) << 8;
      nibB |= ((uint32_t)__shfl_down((int)nibB, 1)) << 4;
      nibB |= ((uint32_t)__shfl_down((int)nibB, 2)) << 8;
      if ((tid & 3) == 0) {
        kn[r0 * 64 + (n >> 2)] = (ushort_t)(nibA & 0xFFFFu);
        kn[r1 * 64 + (n >> 2)] = (ushort_t)(nibA >> 16);
        kn[r2 * 64 + (n >> 2)] = (ushort_t)(nibB & 0xFFFFu);
        kn[r3 * 64 + (n >> 2)] = (ushort_t)(nibB >> 16);
      }
    }
    __syncthreads();
  }

  // ================= decoder =================
  for (int t = 0; t < NS; ++t) {
    // LSTM matvec (dec weights)
    float4 acc = make_float4(0.f, 0.f, 0.f, 0.f);
    {
      const float* wt = decT + tid;
      const float4* hv4 = (const float4*)h4;
#pragma unroll 8
      for (int k = 0; k < 256; ++k) {
        float4 hv = hv4[k];
        float w = wt[(size_t)k * 1024];
        acc.x = fmaf(w, hv.x, acc.x);
        acc.y = fmaf(w, hv.y, acc.y);
        acc.z = fmaf(w, hv.z, acc.z);
        acc.w = fmaf(w, hv.w, acc.w);
      }
    }
    {
      float4 v;
      if (t == 0) {
        v.x = acc.x + bsd + d0p;
        v.y = acc.y + bsd + d0p;
        v.z = acc.z + bsd + d0p;
        v.w = acc.w + bsd + d0p;
      } else {
        int c0 = chs[0], c1 = chs[1], c2 = chs[2], c3 = chs[3];
        v.x = acc.x + bsd + xs[2 * c0] * fad + xs[2 * c0 + 1] * fbd;
        v.y = acc.y + bsd + xs[256 + 2 * c1] * fad + xs[256 + 2 * c1 + 1] * fbd;
        v.z = acc.z + bsd + xs[512 + 2 * c2] * fad + xs[512 + 2 * c2 + 1] * fbd;
        v.w = acc.w + bsd + xs[768 + 2 * c3] * fad + xs[768 + 2 * c3 + 1] * fbd;
      }
      *(float4*)gx[tid] = v;
    }
    __syncthreads();
    {
      float gi = gx[e_own][r_own], gf = gx[e_own + 256][r_own];
      float gg = gx[e_own + 512][r_own], go = gx[e_own + 768][r_own];
      c_own = sigm(gf) * c_own + sigm(gi) * tanhf(gg);
      h_own = sigm(go) * tanhf(c_own);
      h4[e_own][r_own] = h_own;
    }
    __syncthreads();

    // phase 1: qg = g_Wq . h — split-k-4, one weight load feeds all 4 rows
    {
      const int o = tid & 255, kq = tid >> 8;
      const float* wc = gWT + (size_t)kq * 64 * 256 + o;
      const float4* hv4 = (const float4*)h4;
      float4 a = make_float4(0.f, 0.f, 0.f, 0.f);
#pragma unroll 8
      for (int k = 0; k < 64; ++k) {
        float w = wc[(size_t)k * 256];
        float4 hv = hv4[kq * 64 + k];
        a.x = fmaf(w, hv.x, a.x);
        a.y = fmaf(w, hv.y, a.y);
        a.z = fmaf(w, hv.z, a.z);
        a.w = fmaf(w, hv.w, a.w);
      }
      ((float4*)part)[(size_t)kq * 256 + o] = a;
    }
    __syncthreads();
    // phase 1 combine + v-load + gumbel noise precompute
    {
      const int o = tid & 255, r = tid >> 8;
      const float* pf = (const float*)part;
      qs[r][o] = gqb[o] + pf[o * 4 + r] + pf[1024 + o * 4 + r] +
                 pf[2048 + o * 4 + r] + pf[3072 + o * 4 + r];
      vsm[r][o] = gvw[o];
      if (o < NS) {
        uint32_t i = (uint32_t)((bb + r) * NS + o);
        uint2 sk = skeys[t];
        uint32_t o0, o1;
        tf2x32(sk.x, sk.y, 0u, i, o0, o1);
        uint32_t bits = o0 ^ o1;
        float u = __uint_as_float((bits >> 9) | 0x3f800000u) - 1.0f;
        u = u + 1.17549435e-38f;
        u = fmaxf(u, 1.17549435e-38f);
        sv[r][o] = -logf(-logf(u));
      }
    }
    __syncthreads();

    // phase 2: glimpse attention — bounded logits, no max tracking, mask-skip
    {
      const int grp = tid >> 8, gt = tid & 255;
      const int wv = gt >> 6, lane = gt & 63, h0 = lane * 4;
      const float vbias = gvb[0];
      float4 qv = *(const float4*)&qs[grp][h0];
      float v0 = vsm[grp][h0], v1 = vsm[grp][h0 + 1], v2 = vsm[grp][h0 + 2], v3 = vsm[grp][h0 + 3];
      float l = 0.f;
      float4 acc2 = make_float4(0.f, 0.f, 0.f, 0.f);
#pragma unroll 2
      for (int si = 0; si < 32; ++si) {
        int s = wv * 32 + si;
        if (msk[grp][s]) continue;   // wave-uniform skip
        size_t row = (size_t)(bb + grp) * NS + s;
        float4 kv = key_load(gkh, gk8, gkn, row, h0);
        float p = fast_tanh(qv.x + kv.x) * v0 + fast_tanh(qv.y + kv.y) * v1 +
                  fast_tanh(qv.z + kv.z) * v2 + fast_tanh(qv.w + kv.w) * v3;
#pragma unroll
        for (int off = 32; off; off >>= 1) p += __shfl_xor(p, off);
        float pe = expf(10.0f * tanhf(p + vbias));   // logit in [-10,10]: safe
        acc2.x = fmaf(pe, kv.x, acc2.x);
        acc2.y = fmaf(pe, kv.y, acc2.y);
        acc2.z = fmaf(pe, kv.z, acc2.z);
        acc2.w = fmaf(pe, kv.w, acc2.w);
        l += pe;
      }
      *(float4*)&part[grp][wv][h0] = acc2;
      if (lane == 0) wl[grp][wv] = l;
    }
    __syncthreads();
    // phase 2 combine -> qq (k-major), switch v to pointer head
    {
      const int o = tid & 255, r = tid >> 8;
      float den = wl[r][0] + wl[r][1] + wl[r][2] + wl[r][3];
      float num = part[r][0][o] + part[r][1][o] + part[r][2][o] + part[r][3][o];
      qq[o][r] = num / den;
      vsm[r][o] = pvw[o];
    }
    __syncthreads();

    // phase 3: qp = p_Wq . query — split-k-4, 4 rows per weight load
    {
      const int o = tid & 255, kq = tid >> 8;
      const float* wc = pWT + (size_t)kq * 64 * 256 + o;
      const float4* qv4 = (const float4*)qq;
      float4 a = make_float4(0.f, 0.f, 0.f, 0.f);
#pragma unroll 8
      for (int k = 0; k < 64; ++k) {
        float w = wc[(size_t)k * 256];
        float4 hv = qv4[kq * 64 + k];
        a.x = fmaf(w, hv.x, a.x);
        a.y = fmaf(w, hv.y, a.y);
        a.z = fmaf(w, hv.z, a.z);
        a.w = fmaf(w, hv.w, a.w);
      }
      ((float4*)part)[(size_t)kq * 256 + o] = a;
    }
    __syncthreads();
    {
      const int o = tid & 255, r = tid >> 8;
      const float* pf = (const float*)part;
      qs[r][o] = pqb[o] + pf[o * 4 + r] + pf[1024 + o * 4 + r] +
                 pf[2048 + o * 4 + r] + pf[3072 + o * 4 + r];
    }
    __syncthreads();

    // phase 4: pointer logits (mask-skip)
    {
      const int grp = tid >> 8, gt = tid & 255;
      const int wv = gt >> 6, lane = gt & 63, h0 = lane * 4;
      const float vbias = pvb[0];
      float4 qv = *(const float4*)&qs[grp][h0];
      float v0 = vsm[grp][h0], v1 = vsm[grp][h0 + 1], v2 = vsm[grp][h0 + 2], v3 = vsm[grp][h0 + 3];
#pragma unroll 2
      for (int si = 0; si < 32; ++si) {
        int s = wv * 32 + si;
        if (msk[grp][s]) {
          if (lane == 0) lgs[grp][s] = -100000.0f;
          continue;
        }
        size_t row = (size_t)(bb + grp) * NS + s;
        float4 kv = key_load(pkh, pk8, pkn, row, h0);
        float p = fast_tanh(qv.x + kv.x) * v0 + fast_tanh(qv.y + kv.y) * v1 +
                  fast_tanh(qv.z + kv.z) * v2 + fast_tanh(qv.w + kv.w) * v3;
#pragma unroll
        for (int off = 32; off; off >>= 1) p += __shfl_down(p, off);
        if (lane == 0) lgs[grp][s] = 10.0f * tanhf(p + vbias);
      }
    }
    __syncthreads();

    // fused LSE + gumbel argmax + writeout: wave 0 of each group
    if (((tid & 255) >> 6) == 0) {
      const int grp = tid >> 8, lane = tid & 63;
      float a0 = lgs[grp][lane], a1 = lgs[grp][lane + 64];
      float es = expf(a0) + expf(a1);          // exp(-1e5) flushes to 0
      float b0 = a0 + sv[grp][lane], b1 = a1 + sv[grp][lane + 64];
      float bv; int bi;
      if (b1 > b0) { bv = b1; bi = lane + 64; } else { bv = b0; bi = lane; }
#pragma unroll
      for (int off = 32; off; off >>= 1) {
        es += __shfl_xor(es, off);
        float ov = __shfl_down(bv, off);
        int oi = __shfl_down(bi, off);
        if (ov > bv) { bv = ov; bi = oi; }
      }
      if (lane == 0) {
        int cs = bi;
        out[(size_t)(bb + grp) * NS + t] = lgs[grp][cs] - logf(es);
        out[(size_t)NB * NS + (size_t)(bb + grp) * NS + t] = (float)cs;
        msk[grp][cs] = 1;
        chs[grp] = cs;
      }
    }
    __syncthreads();
  }
}

extern "C" void kernel_launch(void* const* d_in, const int* in_sizes, int n_in,
                              void* d_out, int out_size, void* d_ws, size_t ws_size,
                              hipStream_t stream) {
  const float* x        = (const float*)d_in[0];
  const float* emb_W    = (const float*)d_in[1];
  const float* enc_W_ih = (const float*)d_in[2];
  const float* enc_W_hh = (const float*)d_in[3];
  const float* enc_b_ih = (const float*)d_in[4];
  const float* enc_b_hh = (const float*)d_in[5];
  const float* dec_W_ih = (const float*)d_in[6];
  const float* dec_W_hh = (const float*)d_in[7];
  const float* dec_b_ih = (const float*)d_in[8];
  const float* dec_b_hh = (const float*)d_in[9];
  const float* g_Wq_w = (const float*)d_in[10];
  const float* g_Wq_b = (const float*)d_in[11];
  const float* g_Wk_w = (const float*)d_in[12];
  const float* g_Wk_b = (const float*)d_in[13];
  const float* g_v_w  = (const float*)d_in[14];
  const float* g_v_b  = (const float*)d_in[15];
  const float* p_Wq_w = (const float*)d_in[16];
  const float* p_Wq_b = (const float*)d_in[17];
  const float* p_Wk_w = (const float*)d_in[18];
  const float* p_Wk_b = (const float*)d_in[19];
  const float* p_v_w  = (const float*)d_in[20];
  const float* p_v_b  = (const float*)d_in[21];
  const float* dec_start = (const float*)d_in[22];
  (void)in_sizes; (void)n_in;

  const size_t KELEM = (size_t)NB * NS * NH;   // 33.55M per head
  char* w = (char*)d_ws;
  size_t off = 0;
  auto alloc = [&](size_t bytes) -> void* {
    void* p = w + off;
    off += (bytes + 255) & ~(size_t)255;
    return p;
  };
  // quantized keys: 3.5 B/elem, both heads = 224 MiB total
  ushort_t* gkh = (ushort_t*)alloc(KELEM * 2);
  uchar_t*  gk8 = (uchar_t*)alloc(KELEM);
  ushort_t* gkn = (ushort_t*)alloc(KELEM / 2);
  ushort_t* pkh = (ushort_t*)alloc(KELEM * 2);
  uchar_t*  pk8 = (uchar_t*)alloc(KELEM);
  ushort_t* pkn = (ushort_t*)alloc(KELEM / 2);

  float* encT   = (float*)alloc(1024 * 256 * 4);
  float* decT   = (float*)alloc(1024 * 256 * 4);
  float* WkT    = (float*)alloc(512 * 256 * 4);
  float* gWT    = (float*)alloc(256 * 256 * 4);
  float* pWT    = (float*)alloc(256 * 256 * 4);
  float* F_enc  = (float*)alloc(2048 * 4);
  float* F_dec  = (float*)alloc(2048 * 4);
  float* d0proj = (float*)alloc(1024 * 4);
  uint2* skeys  = (uint2*)alloc(NS * 8);

  if (off > ws_size) {
    diag_fill<<<(out_size + 255) / 256, 256, 0, stream>>>((float*)d_out, (float)ws_size, out_size);
    return;
  }

  prep_kernel<<<4, 256, 0, stream>>>(emb_W, enc_W_ih, dec_W_ih, dec_start,
                                     F_enc, F_dec, d0proj, skeys);
  transpose_all<<<256, 1024, 0, stream>>>(enc_W_hh, dec_W_hh, g_Wk_w, p_Wk_w,
                                          g_Wq_w, p_Wq_w, encT, decT, WkT, gWT, pWT);
  net_kernel<<<NB / 4, 1024, 0, stream>>>(
      x, encT, decT, enc_b_ih, enc_b_hh, dec_b_ih, dec_b_hh,
      F_enc, F_dec, d0proj, WkT, g_Wk_b, p_Wk_b,
      gWT, pWT, g_Wq_b, p_Wq_b, g_v_w, g_v_b, p_v_w, p_v_b,
      gkh, gk8, gkn, pkh, pk8, pkn, skeys, (float*)d_out);
}